// Round 13
// baseline (127.592 us; speedup 1.0000x reference)
//
#include <hip/hip_runtime.h>

// ---------------- types / helpers ----------------
typedef __attribute__((ext_vector_type(8))) __bf16 bf16x8;
typedef __attribute__((ext_vector_type(8))) short short8;
typedef __attribute__((ext_vector_type(4))) float f32x4;
typedef unsigned int u32;

static __device__ __forceinline__ unsigned short f2bf(float f) {
    u32 u = __float_as_uint(f);
    u += 0x7FFFu + ((u >> 16) & 1u);
    return (unsigned short)(u >> 16);
}
static __device__ __forceinline__ u32 cvt_pk_bf16(float lo, float hi) {
    u32 r;
    asm("v_cvt_pk_bf16_f32 %0, %1, %2" : "=v"(r) : "v"(lo), "v"(hi));
    return r;
}
static __device__ __forceinline__ bf16x8 as_bf16x8(short8 v) {
    return __builtin_bit_cast(bf16x8, v);
}
static __device__ __forceinline__ f32x4 mfma16(short8 a, short8 b, f32x4 c) {
    return __builtin_amdgcn_mfma_f32_16x16x32_bf16(as_bf16x8(a), as_bf16x8(b), c, 0, 0, 0);
}

// problem sizes
#define NB 8
#define NS 5
#define NQ 15
// ws layout (floats)
#define A_OFF_F 0
#define B_OFF_F (640*256)                        // 163840
#define XF_OFF_F (B_OFF_F + 1920*256)            // 655360
#define WF_OFF_BYTES ((XF_OFF_F + 600*1024)*4)   // 5079040, 16B aligned
#define WF1_OFF_BYTES (WF_OFF_BYTES + 48*8192)   // g-frags 384KB, then W1-frags

// ---------------- kernel A: all weight fragments ----------------
// blocks 0..47: g_w2/3/4 -> bf16 A-frag chunks, chunk cid = L*16+tt at byte cid*8192;
//   within: kk*1024 + lane*16; lane l holds W[k=kk*32+(l>>4)*8+j][outcol=tt*16+(l&15)].
// blocks 48..79: W1 frags (K padded 258->288): chunk c1 = S*16+tt at wf1 + c1*9216.
__global__ void kA(const float* __restrict__ w2, const float* __restrict__ w3,
                   const float* __restrict__ w4, const float* __restrict__ w1,
                   unsigned short* __restrict__ wf, unsigned short* __restrict__ wf1) {
    int bid = blockIdx.x;
    int l = threadIdx.x;
    if (bid < 48) {
        int L = bid >> 4, tt = bid & 15;
        const float* W = (L == 0) ? w2 : ((L == 1) ? w3 : w4);
        int nn = tt * 16 + (l & 15);
        #pragma unroll
        for (int kk = 0; kk < 8; ++kk) {
            int k0 = kk * 32 + (l >> 4) * 8;
            short8 ov;
            #pragma unroll
            for (int j = 0; j < 8; ++j)
                ov[j] = (short)f2bf(W[(size_t)(k0 + j) * 256 + nn]);
            *(short8*)((char*)wf + (size_t)bid * 8192 + kk * 1024 + l * 16) = ov;
        }
        return;
    }
    int c1 = bid - 48;                 // S*16 + tt
    int S = c1 >> 4, tt = c1 & 15;
    int nn = tt * 16 + (l & 15);
    for (int kk = 0; kk < 9; ++kk) {
        int k0 = kk * 32 + (l >> 4) * 8;
        short8 ov;
        #pragma unroll
        for (int j = 0; j < 8; ++j) {
            int kb = k0 + j;
            float v = (kb < 258) ? w1[(size_t)(S * 258 + kb) * 256 + nn] : 0.0f;
            ov[j] = (short)f2bf(v);
        }
        *(short8*)((char*)wf1 + (size_t)c1 * 9216 + kk * 1024 + l * 16) = ov;
    }
}

// ---------------- kernel B: layer-1 rows via MFMA ----------------
// (unchanged from round 12 — verified)
__launch_bounds__(512, 1)
__global__ void kB(const float* __restrict__ sup, const float* __restrict__ qry,
                   const unsigned short* __restrict__ wf1,
                   const float* __restrict__ gb1, float* __restrict__ ws) {
    __shared__ short Xf[18432];       // 36 KB: frag(m,kk) at (m*9+kk)*1024 bytes
    int bid = blockIdx.x;
    bool isA = (bid < 10);
    int S = isA ? 0 : 1;
    int cellbase = isA ? bid * 4 : (bid - 10) * 4;
    const float* src = isA ? sup : qry;
    float* dst0 = ws + (isA ? A_OFF_F : B_OFF_F);
    int t = threadIdx.x;
    int w = t >> 6, l = t & 63;
    int g = l >> 4, c = l & 15;
    char* Xb = (char*)Xf;
    const char* w1b = (const char*)wf1;

    for (int idx = w; idx < 36; idx += 8) {
        int m = idx / 9, kk = idx % 9;
        const float* xp = src + (size_t)(cellbase + m) * 4096;
        int kbase = kk * 32 + g * 8;
        float v[8];
        #pragma unroll
        for (int j = 0; j < 8; ++j) {
            int kb = kbase + j;
            float x;
            if (kb < 256)       x = xp[(size_t)kb * 16 + c];
            else if (kb == 256) x = (float)(c >> 2) * 0.25f;
            else if (kb == 257) x = (float)(c & 3) * 0.25f;
            else                x = 0.0f;
            v[j] = x;
        }
        uint4 hv;
        hv.x = cvt_pk_bf16(v[0], v[1]);
        hv.y = cvt_pk_bf16(v[2], v[3]);
        hv.z = cvt_pk_bf16(v[4], v[5]);
        hv.w = cvt_pk_bf16(v[6], v[7]);
        *(uint4*)(Xb + (size_t)(m * 9 + kk) * 1024 + l * 16) = hv;
    }
    __syncthreads();

    int wp = w >> 2, wn = w & 3;
    const char* wbase = w1b + (size_t)(S * 16 + wn * 4) * 9216;
    short8 wcur[4];
    #pragma unroll
    for (int tti = 0; tti < 4; ++tti)
        wcur[tti] = *(const short8*)(wbase + (size_t)tti * 9216 + l * 16);

    f32x4 acc[2][4];
    #pragma unroll
    for (int pg = 0; pg < 2; ++pg)
        #pragma unroll
        for (int tti = 0; tti < 4; ++tti)
            acc[pg][tti] = (f32x4){0.f, 0.f, 0.f, 0.f};

    #pragma unroll
    for (int kk = 0; kk < 9; ++kk) {
        int kn = kk + 1; if (kn > 8) kn = 8;
        short8 wnxt[4];
        #pragma unroll
        for (int tti = 0; tti < 4; ++tti)
            wnxt[tti] = *(const short8*)(wbase + (size_t)tti * 9216 + kn * 1024 + l * 16);
        #pragma unroll
        for (int pg = 0; pg < 2; ++pg) {
            short8 h = *(const short8*)(Xb + (size_t)((wp * 2 + pg) * 9 + kk) * 1024 + l * 16);
            #pragma unroll
            for (int tti = 0; tti < 4; ++tti)
                acc[pg][tti] = mfma16(wcur[tti], h, acc[pg][tti]);
        }
        #pragma unroll
        for (int tti = 0; tti < 4; ++tti) wcur[tti] = wnxt[tti];
    }

    #pragma unroll
    for (int tti = 0; tti < 4; ++tti) {
        int col0 = wn * 64 + tti * 16 + g * 4;
        float4 bv = {0.f, 0.f, 0.f, 0.f};
        if (S == 0) bv = *(const float4*)(gb1 + col0);
        #pragma unroll
        for (int pg = 0; pg < 2; ++pg) {
            int row = (cellbase + wp * 2 + pg) * 16 + c;
            float4 o;
            o.x = acc[pg][tti][0] + bv.x;
            o.y = acc[pg][tti][1] + bv.y;
            o.z = acc[pg][tti][2] + bv.z;
            o.w = acc[pg][tti][3] + bv.w;
            *(float4*)(dst0 + (size_t)row * 256 + col0) = o;
        }
    }
}

// ---------------- kernel 3: g-MLP layers 2..4 + pair-sum (64-pair blocks) ----------------
// grid = 2400 blocks = (cell, quarter): 64 pairs each. 256 threads = 4 waves.
// Wave w owns outcols [w*64,+64) for all 64 pairs (frags m=0..3); acc[4][4] = 64 regs.
// H: 32 KB -> 4 blocks/CU -> 4 waves/SIMD from 4 INDEPENDENT blocks at drifting
// phases (cross-block overlap hides barriers/epilogues). W: global->reg stream,
// static parity double-buffer (no copies). setprio(1) around the MFMA cluster.
#define K3_STEP(CUR, NXT, KK)                                                   \
    {                                                                           \
        int s = L * 8 + (KK) + 1; if (s > 23) s = 23;                           \
        int Ln = s >> 3, kn = s & 7;                                            \
        _Pragma("unroll")                                                       \
        for (int tti = 0; tti < 4; ++tti)                                       \
            NXT[tti] = *(const short8*)(wfb +                                   \
                (size_t)(Ln * 16 + w * 4 + tti) * 8192 + kn * 1024 + l * 16);   \
        short8 h0 = *(const short8*)(Hb + (size_t)(0 * 8 + (KK)) * 1024 + l * 16); \
        short8 h1 = *(const short8*)(Hb + (size_t)(1 * 8 + (KK)) * 1024 + l * 16); \
        short8 h2 = *(const short8*)(Hb + (size_t)(2 * 8 + (KK)) * 1024 + l * 16); \
        short8 h3 = *(const short8*)(Hb + (size_t)(3 * 8 + (KK)) * 1024 + l * 16); \
        __builtin_amdgcn_s_setprio(1);                                          \
        _Pragma("unroll")                                                       \
        for (int tti = 0; tti < 4; ++tti) {                                     \
            acc[0][tti] = mfma16(CUR[tti], h0, acc[0][tti]);                    \
            acc[1][tti] = mfma16(CUR[tti], h1, acc[1][tti]);                    \
            acc[2][tti] = mfma16(CUR[tti], h2, acc[2][tti]);                    \
            acc[3][tti] = mfma16(CUR[tti], h3, acc[3][tti]);                    \
        }                                                                       \
        __builtin_amdgcn_s_setprio(0);                                          \
    }

__launch_bounds__(256, 4)
__global__ void k3_g(const float* __restrict__ wsA, const float* __restrict__ wsB,
                     const unsigned short* __restrict__ wf,
                     const float* __restrict__ gb2, const float* __restrict__ gb3,
                     const float* __restrict__ gb4, float* __restrict__ xf) {
    __shared__ short Hf[16384];   // 32 KB: frag(m,kk) at (m*8+kk)*1024 bytes, m 0..3
    __shared__ float bs[768];
    int bid = blockIdx.x;
    int bqs = bid >> 2, quarter = bid & 3;
    int b = bqs / 75, rem = bqs % 75, qi = rem / 5, si = rem % 5;
    int t = threadIdx.x;
    int w = t >> 6, l = t & 63;
    int g = l >> 4, c = l & 15;
    char* Hb = (char*)Hf;
    const char* wfb = (const char*)wf;

    bs[t] = gb2[t]; bs[256 + t] = gb3[t]; bs[512 + t] = gb4[t];

    // W step (L=0,kk=0) -> wb0 (lands under phase 1)
    short8 wb0[4], wb1[4];
    #pragma unroll
    for (int tti = 0; tti < 4; ++tti)
        wb0[tti] = *(const short8*)(wfb + (size_t)(w * 4 + tti) * 8192 + l * 16);

    // ---- phase 1: wave w fills frag m=w: support col = c, query row = quarter*4+w
    {
        const float* Arow = wsA + (size_t)(b * NS + si) * 4096 + c * 256;
        const float* Brow = wsB + (size_t)(b * NQ + qi) * 4096 + (quarter * 4 + w) * 256;
        #pragma unroll
        for (int kk = 0; kk < 8; ++kk) {
            const float* ap = Arow + kk * 32 + g * 8;
            const float* bp = Brow + kk * 32 + g * 8;
            float4 a0 = *(const float4*)ap, a1 = *(const float4*)(ap + 4);
            float4 b0 = *(const float4*)bp, b1 = *(const float4*)(bp + 4);
            uint4 hv;
            hv.x = cvt_pk_bf16(fmaxf(a0.x + b0.x, 0.f), fmaxf(a0.y + b0.y, 0.f));
            hv.y = cvt_pk_bf16(fmaxf(a0.z + b0.z, 0.f), fmaxf(a0.w + b0.w, 0.f));
            hv.z = cvt_pk_bf16(fmaxf(a1.x + b1.x, 0.f), fmaxf(a1.y + b1.y, 0.f));
            hv.w = cvt_pk_bf16(fmaxf(a1.z + b1.z, 0.f), fmaxf(a1.w + b1.w, 0.f));
            *(uint4*)(Hb + (size_t)(w * 8 + kk) * 1024 + l * 16) = hv;
        }
    }
    __syncthreads();   // H1 complete + biases staged

    #pragma unroll 1
    for (int L = 0; L < 3; ++L) {
        f32x4 acc[4][4];
        #pragma unroll
        for (int pg = 0; pg < 4; ++pg)
            #pragma unroll
            for (int tti = 0; tti < 4; ++tti)
                acc[pg][tti] = (f32x4){0.f, 0.f, 0.f, 0.f};

        #pragma unroll
        for (int kk2 = 0; kk2 < 4; ++kk2) {
            K3_STEP(wb0, wb1, kk2 * 2)
            K3_STEP(wb1, wb0, kk2 * 2 + 1)
        }
        // kk=7 prefetched (L+1)'s kk=0 into wb0 -> ready for next layer.

        float4 bv[4];
        #pragma unroll
        for (int tti = 0; tti < 4; ++tti)
            bv[tti] = *(const float4*)(bs + L * 256 + w * 64 + tti * 16 + g * 4);

        if (L < 2) {
            __syncthreads();   // all H reads of layer L done
            // scatter relu(acc+bias) -> next-layer frags:
            // m = pg; kk' = w*2+(tti>>1); dlane = ((tti&1)*2+(g>>1))*16 + c; byte (g&1)*8
            #pragma unroll
            for (int pg = 0; pg < 4; ++pg) {
                #pragma unroll
                for (int tti = 0; tti < 4; ++tti) {
                    uint2 q;
                    q.x = cvt_pk_bf16(fmaxf(acc[pg][tti][0] + bv[tti].x, 0.f),
                                      fmaxf(acc[pg][tti][1] + bv[tti].y, 0.f));
                    q.y = cvt_pk_bf16(fmaxf(acc[pg][tti][2] + bv[tti].z, 0.f),
                                      fmaxf(acc[pg][tti][3] + bv[tti].w, 0.f));
                    int kk2 = w * 2 + (tti >> 1);
                    int dlane = ((tti & 1) * 2 + (g >> 1)) * 16 + c;
                    *(uint2*)(Hb + (size_t)(pg * 8 + kk2) * 1024 + dlane * 16 + (g & 1) * 8) = q;
                }
            }
            __syncthreads();   // next layer's H published
        } else {
            // final layer: relu + sum over this block's 64 pairs (4 pg in-reg, 16 c shfl)
            #pragma unroll
            for (int tti = 0; tti < 4; ++tti) {
                float s0 = 0.f, s1 = 0.f, s2 = 0.f, s3 = 0.f;
                #pragma unroll
                for (int pg = 0; pg < 4; ++pg) {
                    s0 += fmaxf(acc[pg][tti][0] + bv[tti].x, 0.f);
                    s1 += fmaxf(acc[pg][tti][1] + bv[tti].y, 0.f);
                    s2 += fmaxf(acc[pg][tti][2] + bv[tti].z, 0.f);
                    s3 += fmaxf(acc[pg][tti][3] + bv[tti].w, 0.f);
                }
                #pragma unroll
                for (int d = 1; d < 16; d <<= 1) {
                    s0 += __shfl_xor(s0, d); s1 += __shfl_xor(s1, d);
                    s2 += __shfl_xor(s2, d); s3 += __shfl_xor(s3, d);
                }
                if (c == 0) {
                    float4 o = {s0, s1, s2, s3};
                    *(float4*)(xf + ((size_t)bqs * 4 + quarter) * 256 +
                               w * 64 + tti * 16 + g * 4) = o;
                }
            }
        }
    }
}

// ---------------- kernel 4: f-MLP + sigmoid + MSE loss ----------------
// grid = 150 blocks x 4 cells, 256 threads; fw loads reused 4x.
__global__ void k4_f(const float* __restrict__ xf,
                     const float* __restrict__ fw1, const float* __restrict__ fb1,
                     const float* __restrict__ fw2, const float* __restrict__ fb2,
                     const float* __restrict__ fw3, const float* __restrict__ fb3,
                     const float* __restrict__ fw4, const float* __restrict__ fb4,
                     const int* __restrict__ sy, const int* __restrict__ qy,
                     float* __restrict__ out) {
    __shared__ float xb[4][256], yb[4][256], y3[4][32];
    int base = blockIdx.x * 4;
    int t = threadIdx.x;
    #pragma unroll
    for (int cc = 0; cc < 4; ++cc) {
        const float* xr = xf + (size_t)(base + cc) * 1024 + t;
        xb[cc][t] = xr[0] + xr[256] + xr[512] + xr[768];
    }
    __syncthreads();
    float acc[4];
    #pragma unroll
    for (int cc = 0; cc < 4; ++cc) acc[cc] = fb1[t];
    #pragma unroll 8
    for (int k = 0; k < 256; ++k) {
        float wv = fw1[(size_t)k * 256 + t];
        #pragma unroll
        for (int cc = 0; cc < 4; ++cc) acc[cc] += xb[cc][k] * wv;
    }
    #pragma unroll
    for (int cc = 0; cc < 4; ++cc) yb[cc][t] = acc[cc] > 0.f ? acc[cc] : 0.f;
    __syncthreads();
    #pragma unroll
    for (int cc = 0; cc < 4; ++cc) acc[cc] = fb2[t];
    #pragma unroll 8
    for (int k = 0; k < 256; ++k) {
        float wv = fw2[(size_t)k * 256 + t];
        #pragma unroll
        for (int cc = 0; cc < 4; ++cc) acc[cc] += yb[cc][k] * wv;
    }
    #pragma unroll
    for (int cc = 0; cc < 4; ++cc) xb[cc][t] = acc[cc] > 0.f ? acc[cc] : 0.f;
    __syncthreads();
    if (t < 116) {
        int cc = t / 29, col = t % 29;
        float a = fb3[col];
        #pragma unroll 8
        for (int k = 0; k < 256; ++k) a += xb[cc][k] * fw3[(size_t)k * 29 + col];
        y3[cc][col] = a > 0.f ? a : 0.f;
    }
    __syncthreads();
    if (t < 4) {
        int cc = t;
        float z = fb4[0];
        for (int k = 0; k < 29; ++k) z += y3[cc][k] * fw4[k];
        float score = 1.0f / (1.0f + __expf(-z));
        int bqs = base + cc;
        int b = bqs / 75, rem = bqs % 75, qi = rem / 5, si = rem % 5;
        float label = (sy[b * NS + si] == qy[b * NQ + qi]) ? 1.0f : 0.0f;
        float d = label - score;
        atomicAdd(out, d * d * 0.125f);
    }
}

// ---------------- launch ----------------
extern "C" void kernel_launch(void* const* d_in, const int* in_sizes, int n_in,
                              void* d_out, int out_size, void* d_ws, size_t ws_size,
                              hipStream_t stream) {
    const float* sup = (const float*)d_in[0];
    const float* qry = (const float*)d_in[1];
    const int*   sy  = (const int*)d_in[2];
    const int*   qy  = (const int*)d_in[3];
    const float* gw1 = (const float*)d_in[4];
    const float* gb1 = (const float*)d_in[5];
    const float* gw2 = (const float*)d_in[6];
    const float* gb2 = (const float*)d_in[7];
    const float* gw3 = (const float*)d_in[8];
    const float* gb3 = (const float*)d_in[9];
    const float* gw4 = (const float*)d_in[10];
    const float* gb4 = (const float*)d_in[11];
    const float* fw1 = (const float*)d_in[12];
    const float* fb1 = (const float*)d_in[13];
    const float* fw2 = (const float*)d_in[14];
    const float* fb2 = (const float*)d_in[15];
    const float* fw3 = (const float*)d_in[16];
    const float* fb3 = (const float*)d_in[17];
    const float* fw4 = (const float*)d_in[18];
    const float* fb4 = (const float*)d_in[19];

    float* ws = (float*)d_ws;
    float* A  = ws + A_OFF_F;
    float* B  = ws + B_OFF_F;
    float* xf = ws + XF_OFF_F;
    unsigned short* wf  = (unsigned short*)((char*)d_ws + WF_OFF_BYTES);
    unsigned short* wf1 = (unsigned short*)((char*)d_ws + WF1_OFF_BYTES);
    float* out = (float*)d_out;

    hipMemsetAsync(out, 0, sizeof(float), stream);

    kA<<<80, 64, 0, stream>>>(gw2, gw3, gw4, gw1, wf, wf1);
    kB<<<40, 512, 0, stream>>>(sup, qry, wf1, gb1, ws);
    k3_g<<<2400, 256, 0, stream>>>(A, B, wf, gb2, gb3, gb4, xf);
    k4_f<<<150, 256, 0, stream>>>(xf, fw1, fb1, fw2, fb2, fw3, fb3, fw4, fb4, sy, qy, out);
}

// Round 14
// 118.872 us; speedup vs baseline: 1.0734x; 1.0734x over previous
//
#include <hip/hip_runtime.h>

// ---------------- types / helpers ----------------
typedef __attribute__((ext_vector_type(8))) __bf16 bf16x8;
typedef __attribute__((ext_vector_type(8))) short short8;
typedef __attribute__((ext_vector_type(4))) float f32x4;
typedef unsigned int u32;

static __device__ __forceinline__ unsigned short f2bf(float f) {
    u32 u = __float_as_uint(f);
    u += 0x7FFFu + ((u >> 16) & 1u);
    return (unsigned short)(u >> 16);
}
static __device__ __forceinline__ u32 cvt_pk_bf16(float lo, float hi) {
    u32 r;
    asm("v_cvt_pk_bf16_f32 %0, %1, %2" : "=v"(r) : "v"(lo), "v"(hi));
    return r;
}
static __device__ __forceinline__ bf16x8 as_bf16x8(short8 v) {
    return __builtin_bit_cast(bf16x8, v);
}
static __device__ __forceinline__ f32x4 mfma16(short8 a, short8 b, f32x4 c) {
    return __builtin_amdgcn_mfma_f32_16x16x32_bf16(as_bf16x8(a), as_bf16x8(b), c, 0, 0, 0);
}

// problem sizes
#define NB 8
#define NS 5
#define NQ 15
// ws layout (floats / bytes)
#define A_OFF_F 0
#define B_OFF_F (640*256)                        // 163840
#define XF_OFF_F (B_OFF_F + 1920*256)            // 655360
#define WF_OFF_BYTES ((XF_OFF_F + 600*1024)*4)   // 5079040, 16B aligned
#define WF1_OFF_BYTES (WF_OFF_BYTES + 48*8192)   // W1 frags (32 x 9216)
#define WFF_OFF_BYTES (WF1_OFF_BYTES + 32*9216)  // fw1/fw2 frags (32 x 8192)
#define WF3_OFF_BYTES (WFF_OFF_BYTES + 32*8192)  // fw3 frags (2 x 8192)

// ---------------- kernel A: all weight fragments ----------------
// blocks 0..47:   g_w2/3/4 -> wf,  chunk cid = L*16+tt at cid*8192
// blocks 48..79:  W1 (K padded 258->288) -> wf1, chunk c1 = S*16+tt at c1*9216
// blocks 80..111: fw1/fw2 -> wff, chunk cid = Lf*16+tt at cid*8192
// blocks 112..113: fw3 (29 cols zero-padded to 32) -> wf3, chunk tt at tt*8192
// frag layout everywhere: kk*1024 + lane*16; lane l holds
// W[k=kk*32+(l>>4)*8+j][outcol=tt*16+(l&15)], j=0..7 (bf16).
__global__ void kA(const float* __restrict__ w2, const float* __restrict__ w3,
                   const float* __restrict__ w4, const float* __restrict__ w1,
                   const float* __restrict__ fw1, const float* __restrict__ fw2,
                   const float* __restrict__ fw3,
                   unsigned short* __restrict__ wf, unsigned short* __restrict__ wf1,
                   unsigned short* __restrict__ wff, unsigned short* __restrict__ wf3) {
    int bid = blockIdx.x;
    int l = threadIdx.x;
    if (bid < 48) {
        int L = bid >> 4, tt = bid & 15;
        const float* W = (L == 0) ? w2 : ((L == 1) ? w3 : w4);
        int nn = tt * 16 + (l & 15);
        #pragma unroll
        for (int kk = 0; kk < 8; ++kk) {
            int k0 = kk * 32 + (l >> 4) * 8;
            short8 ov;
            #pragma unroll
            for (int j = 0; j < 8; ++j)
                ov[j] = (short)f2bf(W[(size_t)(k0 + j) * 256 + nn]);
            *(short8*)((char*)wf + (size_t)bid * 8192 + kk * 1024 + l * 16) = ov;
        }
        return;
    }
    if (bid < 80) {
        int c1 = bid - 48;                 // S*16 + tt
        int S = c1 >> 4, tt = c1 & 15;
        int nn = tt * 16 + (l & 15);
        for (int kk = 0; kk < 9; ++kk) {
            int k0 = kk * 32 + (l >> 4) * 8;
            short8 ov;
            #pragma unroll
            for (int j = 0; j < 8; ++j) {
                int kb = k0 + j;
                float v = (kb < 258) ? w1[(size_t)(S * 258 + kb) * 256 + nn] : 0.0f;
                ov[j] = (short)f2bf(v);
            }
            *(short8*)((char*)wf1 + (size_t)c1 * 9216 + kk * 1024 + l * 16) = ov;
        }
        return;
    }
    if (bid < 112) {
        int cid = bid - 80;                // Lf*16 + tt
        int Lf = cid >> 4, tt = cid & 15;
        const float* W = (Lf == 0) ? fw1 : fw2;
        int nn = tt * 16 + (l & 15);
        #pragma unroll
        for (int kk = 0; kk < 8; ++kk) {
            int k0 = kk * 32 + (l >> 4) * 8;
            short8 ov;
            #pragma unroll
            for (int j = 0; j < 8; ++j)
                ov[j] = (short)f2bf(W[(size_t)(k0 + j) * 256 + nn]);
            *(short8*)((char*)wff + (size_t)cid * 8192 + kk * 1024 + l * 16) = ov;
        }
        return;
    }
    {
        int tt = bid - 112;                // 0..1
        int nn = tt * 16 + (l & 15);
        #pragma unroll
        for (int kk = 0; kk < 8; ++kk) {
            int k0 = kk * 32 + (l >> 4) * 8;
            short8 ov;
            #pragma unroll
            for (int j = 0; j < 8; ++j) {
                float v = (nn < 29) ? fw3[(size_t)(k0 + j) * 29 + nn] : 0.0f;
                ov[j] = (short)f2bf(v);
            }
            *(short8*)((char*)wf3 + (size_t)tt * 8192 + kk * 1024 + l * 16) = ov;
        }
    }
}

// ---------------- kernel B: layer-1 rows via MFMA (verified, unchanged) ----------------
__launch_bounds__(512, 1)
__global__ void kB(const float* __restrict__ sup, const float* __restrict__ qry,
                   const unsigned short* __restrict__ wf1,
                   const float* __restrict__ gb1, float* __restrict__ ws) {
    __shared__ short Xf[18432];       // 36 KB: frag(m,kk) at (m*9+kk)*1024 bytes
    int bid = blockIdx.x;
    bool isA = (bid < 10);
    int S = isA ? 0 : 1;
    int cellbase = isA ? bid * 4 : (bid - 10) * 4;
    const float* src = isA ? sup : qry;
    float* dst0 = ws + (isA ? A_OFF_F : B_OFF_F);
    int t = threadIdx.x;
    int w = t >> 6, l = t & 63;
    int g = l >> 4, c = l & 15;
    char* Xb = (char*)Xf;
    const char* w1b = (const char*)wf1;

    for (int idx = w; idx < 36; idx += 8) {
        int m = idx / 9, kk = idx % 9;
        const float* xp = src + (size_t)(cellbase + m) * 4096;
        int kbase = kk * 32 + g * 8;
        float v[8];
        #pragma unroll
        for (int j = 0; j < 8; ++j) {
            int kb = kbase + j;
            float x;
            if (kb < 256)       x = xp[(size_t)kb * 16 + c];
            else if (kb == 256) x = (float)(c >> 2) * 0.25f;
            else if (kb == 257) x = (float)(c & 3) * 0.25f;
            else                x = 0.0f;
            v[j] = x;
        }
        uint4 hv;
        hv.x = cvt_pk_bf16(v[0], v[1]);
        hv.y = cvt_pk_bf16(v[2], v[3]);
        hv.z = cvt_pk_bf16(v[4], v[5]);
        hv.w = cvt_pk_bf16(v[6], v[7]);
        *(uint4*)(Xb + (size_t)(m * 9 + kk) * 1024 + l * 16) = hv;
    }
    __syncthreads();

    int wp = w >> 2, wn = w & 3;
    const char* wbase = w1b + (size_t)(S * 16 + wn * 4) * 9216;
    short8 wcur[4];
    #pragma unroll
    for (int tti = 0; tti < 4; ++tti)
        wcur[tti] = *(const short8*)(wbase + (size_t)tti * 9216 + l * 16);

    f32x4 acc[2][4];
    #pragma unroll
    for (int pg = 0; pg < 2; ++pg)
        #pragma unroll
        for (int tti = 0; tti < 4; ++tti)
            acc[pg][tti] = (f32x4){0.f, 0.f, 0.f, 0.f};

    #pragma unroll
    for (int kk = 0; kk < 9; ++kk) {
        int kn = kk + 1; if (kn > 8) kn = 8;
        short8 wnxt[4];
        #pragma unroll
        for (int tti = 0; tti < 4; ++tti)
            wnxt[tti] = *(const short8*)(wbase + (size_t)tti * 9216 + kn * 1024 + l * 16);
        #pragma unroll
        for (int pg = 0; pg < 2; ++pg) {
            short8 h = *(const short8*)(Xb + (size_t)((wp * 2 + pg) * 9 + kk) * 1024 + l * 16);
            #pragma unroll
            for (int tti = 0; tti < 4; ++tti)
                acc[pg][tti] = mfma16(wcur[tti], h, acc[pg][tti]);
        }
        #pragma unroll
        for (int tti = 0; tti < 4; ++tti) wcur[tti] = wnxt[tti];
    }

    #pragma unroll
    for (int tti = 0; tti < 4; ++tti) {
        int col0 = wn * 64 + tti * 16 + g * 4;
        float4 bv = {0.f, 0.f, 0.f, 0.f};
        if (S == 0) bv = *(const float4*)(gb1 + col0);
        #pragma unroll
        for (int pg = 0; pg < 2; ++pg) {
            int row = (cellbase + wp * 2 + pg) * 16 + c;
            float4 o;
            o.x = acc[pg][tti][0] + bv.x;
            o.y = acc[pg][tti][1] + bv.y;
            o.z = acc[pg][tti][2] + bv.z;
            o.w = acc[pg][tti][3] + bv.w;
            *(float4*)(dst0 + (size_t)row * 256 + col0) = o;
        }
    }
}

// ---------------- kernel 3: g-MLP layers 2..4 + pair-sum (R12 verified config) ----------
// grid = 1200 blocks = (cell, half): 128 pairs. 512 threads = 8 waves (wp x wn = 2x4).
__launch_bounds__(512, 4)
__global__ void k3_g(const float* __restrict__ wsA, const float* __restrict__ wsB,
                     const unsigned short* __restrict__ wf,
                     const float* __restrict__ gb2, const float* __restrict__ gb3,
                     const float* __restrict__ gb4, float* __restrict__ xf) {
    __shared__ short Hf[32768];   // 64 KB: frag(m,kk) at (m*8+kk)*1024 bytes, m 0..7
    __shared__ float bs[768];
    int bid = blockIdx.x;
    int bqs = bid >> 1, half = bid & 1;
    int b = bqs / 75, rem = bqs % 75, qi = rem / 5, si = rem % 5;
    int t = threadIdx.x;
    int w = t >> 6, l = t & 63;
    int g = l >> 4, c = l & 15;
    int wp = w >> 2, wn = w & 3;
    char* Hb = (char*)Hf;
    const char* wfb = (const char*)wf;

    if (t < 256) { bs[t] = gb2[t]; bs[256 + t] = gb3[t]; bs[512 + t] = gb4[t]; }

    short8 wcur[4];
    #pragma unroll
    for (int tti = 0; tti < 4; ++tti)
        wcur[tti] = *(const short8*)(wfb + (size_t)(wn * 4 + tti) * 8192 + l * 16);

    {
        const float* Arow = wsA + (size_t)(b * NS + si) * 4096 + c * 256;
        const float* Brow = wsB + (size_t)(b * NQ + qi) * 4096 + (half * 8 + w) * 256;
        #pragma unroll
        for (int kk = 0; kk < 8; ++kk) {
            const float* ap = Arow + kk * 32 + g * 8;
            const float* bp = Brow + kk * 32 + g * 8;
            float4 a0 = *(const float4*)ap, a1 = *(const float4*)(ap + 4);
            float4 b0 = *(const float4*)bp, b1 = *(const float4*)(bp + 4);
            uint4 hv;
            hv.x = cvt_pk_bf16(fmaxf(a0.x + b0.x, 0.f), fmaxf(a0.y + b0.y, 0.f));
            hv.y = cvt_pk_bf16(fmaxf(a0.z + b0.z, 0.f), fmaxf(a0.w + b0.w, 0.f));
            hv.z = cvt_pk_bf16(fmaxf(a1.x + b1.x, 0.f), fmaxf(a1.y + b1.y, 0.f));
            hv.w = cvt_pk_bf16(fmaxf(a1.z + b1.z, 0.f), fmaxf(a1.w + b1.w, 0.f));
            *(uint4*)(Hb + (size_t)(w * 8 + kk) * 1024 + l * 16) = hv;
        }
    }
    __syncthreads();

    #pragma unroll 1
    for (int L = 0; L < 3; ++L) {
        f32x4 acc[4][4];
        #pragma unroll
        for (int pg = 0; pg < 4; ++pg)
            #pragma unroll
            for (int tti = 0; tti < 4; ++tti)
                acc[pg][tti] = (f32x4){0.f, 0.f, 0.f, 0.f};

        #pragma unroll
        for (int kk = 0; kk < 8; ++kk) {
            int s = L * 8 + kk + 1; if (s > 23) s = 23;
            int Ln = s >> 3, kn = s & 7;
            short8 wnxt[4];
            #pragma unroll
            for (int tti = 0; tti < 4; ++tti)
                wnxt[tti] = *(const short8*)(wfb +
                    (size_t)(Ln * 16 + wn * 4 + tti) * 8192 + kn * 1024 + l * 16);
            #pragma unroll
            for (int pg = 0; pg < 4; ++pg) {
                short8 h = *(const short8*)(Hb +
                    (size_t)((wp * 4 + pg) * 8 + kk) * 1024 + l * 16);
                #pragma unroll
                for (int tti = 0; tti < 4; ++tti)
                    acc[pg][tti] = mfma16(wcur[tti], h, acc[pg][tti]);
            }
            #pragma unroll
            for (int tti = 0; tti < 4; ++tti) wcur[tti] = wnxt[tti];
        }

        float4 bv[4];
        #pragma unroll
        for (int tti = 0; tti < 4; ++tti)
            bv[tti] = *(const float4*)(bs + L * 256 + wn * 64 + tti * 16 + g * 4);

        if (L < 2) {
            __syncthreads();
            #pragma unroll
            for (int pg = 0; pg < 4; ++pg) {
                int m = wp * 4 + pg;
                #pragma unroll
                for (int tti = 0; tti < 4; ++tti) {
                    uint2 q;
                    q.x = cvt_pk_bf16(fmaxf(acc[pg][tti][0] + bv[tti].x, 0.f),
                                      fmaxf(acc[pg][tti][1] + bv[tti].y, 0.f));
                    q.y = cvt_pk_bf16(fmaxf(acc[pg][tti][2] + bv[tti].z, 0.f),
                                      fmaxf(acc[pg][tti][3] + bv[tti].w, 0.f));
                    int kk2 = wn * 2 + (tti >> 1);
                    int dlane = ((tti & 1) * 2 + (g >> 1)) * 16 + c;
                    *(uint2*)(Hb + (size_t)(m * 8 + kk2) * 1024 + dlane * 16 + (g & 1) * 8) = q;
                }
            }
            __syncthreads();
        } else {
            #pragma unroll
            for (int tti = 0; tti < 4; ++tti) {
                float s0 = 0.f, s1 = 0.f, s2 = 0.f, s3 = 0.f;
                #pragma unroll
                for (int pg = 0; pg < 4; ++pg) {
                    s0 += fmaxf(acc[pg][tti][0] + bv[tti].x, 0.f);
                    s1 += fmaxf(acc[pg][tti][1] + bv[tti].y, 0.f);
                    s2 += fmaxf(acc[pg][tti][2] + bv[tti].z, 0.f);
                    s3 += fmaxf(acc[pg][tti][3] + bv[tti].w, 0.f);
                }
                #pragma unroll
                for (int d = 1; d < 16; d <<= 1) {
                    s0 += __shfl_xor(s0, d); s1 += __shfl_xor(s1, d);
                    s2 += __shfl_xor(s2, d); s3 += __shfl_xor(s3, d);
                }
                if (c == 0) {
                    float4 o = {s0, s1, s2, s3};
                    *(float4*)(xf + (((size_t)bqs * 2 + half) * 2 + wp) * 256 +
                               wn * 64 + tti * 16 + g * 4) = o;
                }
            }
        }
    }
}

// ---------------- kernel 4: f-MLP via MFMA + sigmoid + MSE loss ----------------
// grid = 10 blocks x 64 rows (600 valid), 512 threads = 8 waves (wp x wn = 2x4).
// Stage xf rows (4-partial sums) into the verified B-frag layout; fw1/fw2 layers
// exactly as k3's inner loop (scatter mapping identical, 4 m-frags); layer 3 as
// one MFMA tile pass (29 cols padded to 32); layer 4 + sigmoid + loss on 64 lanes.
__launch_bounds__(512, 1)
__global__ void k4_f(const float* __restrict__ xf,
                     const unsigned short* __restrict__ wff,
                     const unsigned short* __restrict__ wf3,
                     const float* __restrict__ fb1, const float* __restrict__ fb2,
                     const float* __restrict__ fb3,
                     const float* __restrict__ fw4, const float* __restrict__ fb4,
                     const int* __restrict__ sy, const int* __restrict__ qy,
                     float* __restrict__ out) {
    __shared__ short Hf[16384];   // 32 KB: frag(m,kk) at (m*8+kk)*1024, m 0..3
    __shared__ float bs[512];
    __shared__ float bs3[32];
    __shared__ float y3[64][32];
    int bid = blockIdx.x;
    int t = threadIdx.x;
    int w = t >> 6, l = t & 63;
    int g = l >> 4, c = l & 15;
    char* Hb = (char*)Hf;
    const char* wfb = (const char*)wff;

    bs[t & 511] = (t < 256) ? fb1[t] : fb2[t - 256];
    if (t < 32) bs3[t] = (t < 29) ? fb3[t] : 0.0f;

    // ---- stage 64 rows of xf (sum 4 partials) into B-frag layout
    for (int fi = w; fi < 32; fi += 8) {
        int m = fi >> 3, kk = fi & 7;
        int row = bid * 64 + m * 16 + c;
        if (row > 599) row = 599;
        const float* xr = xf + (size_t)row * 1024;
        int kb = kk * 32 + g * 8;
        float v[8];
        #pragma unroll
        for (int j = 0; j < 8; ++j) {
            int f = kb + j;
            v[j] = xr[f] + xr[256 + f] + xr[512 + f] + xr[768 + f];
        }
        uint4 hv;
        hv.x = cvt_pk_bf16(v[0], v[1]);
        hv.y = cvt_pk_bf16(v[2], v[3]);
        hv.z = cvt_pk_bf16(v[4], v[5]);
        hv.w = cvt_pk_bf16(v[6], v[7]);
        *(uint4*)(Hb + (size_t)(m * 8 + kk) * 1024 + l * 16) = hv;
    }
    __syncthreads();

    int wp = w >> 2, wn = w & 3;
    short8 wcur[4];
    #pragma unroll
    for (int tti = 0; tti < 4; ++tti)
        wcur[tti] = *(const short8*)(wfb + (size_t)(wn * 4 + tti) * 8192 + l * 16);

    #pragma unroll 1
    for (int L = 0; L < 2; ++L) {
        f32x4 acc[2][4];
        #pragma unroll
        for (int pg = 0; pg < 2; ++pg)
            #pragma unroll
            for (int tti = 0; tti < 4; ++tti)
                acc[pg][tti] = (f32x4){0.f, 0.f, 0.f, 0.f};

        #pragma unroll
        for (int kk = 0; kk < 8; ++kk) {
            int s = L * 8 + kk + 1; if (s > 15) s = 15;
            int Ln = s >> 3, kn = s & 7;
            short8 wnxt[4];
            #pragma unroll
            for (int tti = 0; tti < 4; ++tti)
                wnxt[tti] = *(const short8*)(wfb +
                    (size_t)(Ln * 16 + wn * 4 + tti) * 8192 + kn * 1024 + l * 16);
            #pragma unroll
            for (int pg = 0; pg < 2; ++pg) {
                short8 h = *(const short8*)(Hb +
                    (size_t)((wp * 2 + pg) * 8 + kk) * 1024 + l * 16);
                #pragma unroll
                for (int tti = 0; tti < 4; ++tti)
                    acc[pg][tti] = mfma16(wcur[tti], h, acc[pg][tti]);
            }
            #pragma unroll
            for (int tti = 0; tti < 4; ++tti) wcur[tti] = wnxt[tti];
        }

        float4 bv[4];
        #pragma unroll
        for (int tti = 0; tti < 4; ++tti)
            bv[tti] = *(const float4*)(bs + L * 256 + wn * 64 + tti * 16 + g * 4);

        __syncthreads();
        #pragma unroll
        for (int pg = 0; pg < 2; ++pg) {
            int m = wp * 2 + pg;
            #pragma unroll
            for (int tti = 0; tti < 4; ++tti) {
                uint2 q;
                q.x = cvt_pk_bf16(fmaxf(acc[pg][tti][0] + bv[tti].x, 0.f),
                                  fmaxf(acc[pg][tti][1] + bv[tti].y, 0.f));
                q.y = cvt_pk_bf16(fmaxf(acc[pg][tti][2] + bv[tti].z, 0.f),
                                  fmaxf(acc[pg][tti][3] + bv[tti].w, 0.f));
                int kk2 = wn * 2 + (tti >> 1);
                int dlane = ((tti & 1) * 2 + (g >> 1)) * 16 + c;
                *(uint2*)(Hb + (size_t)(m * 8 + kk2) * 1024 + dlane * 16 + (g & 1) * 8) = q;
            }
        }
        __syncthreads();
    }

    // ---- layer 3: 64 rows x 32 cols (29 valid), wave w -> (m = w>>1, tt = w&1)
    {
        int m = w >> 1, tt = w & 1;
        f32x4 a3 = {0.f, 0.f, 0.f, 0.f};
        #pragma unroll
        for (int kk = 0; kk < 8; ++kk) {
            short8 wv = *(const short8*)((const char*)wf3 +
                (size_t)(tt * 8 + kk) * 1024 + l * 16);
            short8 h = *(const short8*)(Hb + (size_t)(m * 8 + kk) * 1024 + l * 16);
            a3 = mfma16(wv, h, a3);
        }
        #pragma unroll
        for (int r = 0; r < 4; ++r) {
            int oc = tt * 16 + g * 4 + r;
            float v = a3[r] + bs3[oc];
            y3[m * 16 + c][oc] = v > 0.f ? v : 0.f;
        }
    }
    __syncthreads();

    // ---- layer 4 + sigmoid + MSE
    if (t < 64) {
        int bqs = bid * 64 + t;
        if (bqs < 600) {
            float z = fb4[0];
            #pragma unroll
            for (int k = 0; k < 29; ++k) z += y3[t][k] * fw4[k];
            float score = 1.0f / (1.0f + __expf(-z));
            int b = bqs / 75, rem = bqs % 75, qi = rem / 5, si = rem % 5;
            float label = (sy[b * NS + si] == qy[b * NQ + qi]) ? 1.0f : 0.0f;
            float d = label - score;
            atomicAdd(out, d * d * 0.125f);
        }
    }
}

// ---------------- launch ----------------
extern "C" void kernel_launch(void* const* d_in, const int* in_sizes, int n_in,
                              void* d_out, int out_size, void* d_ws, size_t ws_size,
                              hipStream_t stream) {
    const float* sup = (const float*)d_in[0];
    const float* qry = (const float*)d_in[1];
    const int*   sy  = (const int*)d_in[2];
    const int*   qy  = (const int*)d_in[3];
    const float* gw1 = (const float*)d_in[4];
    const float* gb1 = (const float*)d_in[5];
    const float* gw2 = (const float*)d_in[6];
    const float* gb2 = (const float*)d_in[7];
    const float* gw3 = (const float*)d_in[8];
    const float* gb3 = (const float*)d_in[9];
    const float* gw4 = (const float*)d_in[10];
    const float* gb4 = (const float*)d_in[11];
    const float* fw1 = (const float*)d_in[12];
    const float* fb1 = (const float*)d_in[13];
    const float* fw2 = (const float*)d_in[14];
    const float* fb2 = (const float*)d_in[15];
    const float* fw3 = (const float*)d_in[16];
    const float* fb3 = (const float*)d_in[17];
    const float* fw4 = (const float*)d_in[18];
    const float* fb4 = (const float*)d_in[19];

    float* ws = (float*)d_ws;
    float* A  = ws + A_OFF_F;
    float* B  = ws + B_OFF_F;
    float* xf = ws + XF_OFF_F;
    unsigned short* wf  = (unsigned short*)((char*)d_ws + WF_OFF_BYTES);
    unsigned short* wf1 = (unsigned short*)((char*)d_ws + WF1_OFF_BYTES);
    unsigned short* wff = (unsigned short*)((char*)d_ws + WFF_OFF_BYTES);
    unsigned short* wf3 = (unsigned short*)((char*)d_ws + WF3_OFF_BYTES);
    float* out = (float*)d_out;

    hipMemsetAsync(out, 0, sizeof(float), stream);

    kA<<<114, 64, 0, stream>>>(gw2, gw3, gw4, gw1, fw1, fw2, fw3, wf, wf1, wff, wf3);
    kB<<<40, 512, 0, stream>>>(sup, qry, wf1, gb1, ws);
    k3_g<<<1200, 512, 0, stream>>>(A, B, wf, gb2, gb3, gb4, xf);
    k4_f<<<10, 512, 0, stream>>>(xf, wff, wf3, fb1, fb2, fb3, fw4, fb4, sy, qy, out);
}

// Round 15
// 111.689 us; speedup vs baseline: 1.1424x; 1.0643x over previous
//
#include <hip/hip_runtime.h>

// ---------------- types / helpers ----------------
typedef __attribute__((ext_vector_type(8))) __bf16 bf16x8;
typedef __attribute__((ext_vector_type(8))) short short8;
typedef __attribute__((ext_vector_type(4))) float f32x4;
typedef unsigned int u32;

static __device__ __forceinline__ unsigned short f2bf(float f) {
    u32 u = __float_as_uint(f);
    u += 0x7FFFu + ((u >> 16) & 1u);
    return (unsigned short)(u >> 16);
}
static __device__ __forceinline__ u32 cvt_pk_bf16(float lo, float hi) {
    u32 r;
    asm("v_cvt_pk_bf16_f32 %0, %1, %2" : "=v"(r) : "v"(lo), "v"(hi));
    return r;
}
static __device__ __forceinline__ bf16x8 as_bf16x8(short8 v) {
    return __builtin_bit_cast(bf16x8, v);
}
static __device__ __forceinline__ f32x4 mfma16(short8 a, short8 b, f32x4 c) {
    return __builtin_amdgcn_mfma_f32_16x16x32_bf16(as_bf16x8(a), as_bf16x8(b), c, 0, 0, 0);
}

// problem sizes
#define NB 8
#define NS 5
#define NQ 15
// ws layout (floats / bytes)
#define A_OFF_F 0
#define B_OFF_F (640*256)                        // 163840
#define XF_OFF_F (B_OFF_F + 1920*256)            // 655360
#define WF_OFF_BYTES ((XF_OFF_F + 600*1024)*4)   // 5079040, 16B aligned
#define WF1_OFF_BYTES (WF_OFF_BYTES + 48*8192)   // W1 frags (32 x 9216)
#define WFF_OFF_BYTES (WF1_OFF_BYTES + 32*9216)  // fw1/fw2 frags (32 x 8192)
#define WF3_OFF_BYTES (WFF_OFF_BYTES + 32*8192)  // fw3 frags (2 x 8192)

// ---------------- kernel A: W1 fragments only (needed by kB) ----------------
// 32 blocks x 64 thr. chunk c1 = S*16+tt at wf1 + c1*9216; within kk*1024 + lane*16
// (kk 0..8, K padded 258->288); lane l holds W1[k=kk*32+(l>>4)*8+j][outcol=tt*16+(l&15)].
__global__ void kA(const float* __restrict__ w1, unsigned short* __restrict__ wf1) {
    int c1 = blockIdx.x;               // S*16 + tt
    int l = threadIdx.x;
    int S = c1 >> 4, tt = c1 & 15;
    int nn = tt * 16 + (l & 15);
    for (int kk = 0; kk < 9; ++kk) {
        int k0 = kk * 32 + (l >> 4) * 8;
        short8 ov;
        #pragma unroll
        for (int j = 0; j < 8; ++j) {
            int kb = k0 + j;
            float v = (kb < 258) ? w1[(size_t)(S * 258 + kb) * 256 + nn] : 0.0f;
            ov[j] = (short)f2bf(v);
        }
        *(short8*)((char*)wf1 + (size_t)c1 * 9216 + kk * 1024 + l * 16) = ov;
    }
}

// ---------------- kernel B: layer-1 via MFMA (1 cell/block) + all later-stage frags ----
// 181 blocks x 256 thr (4 waves):
//   blocks 0..159:  layer-1 for one cell (0..39 sup, 40..159 qry). Verified kB math, m=0.
//   blocks 160..171: g_w2/3/4 -> wf chunks (4 chunks/block, wave-per-chunk)
//   block  172:      fw3 -> wf3 (waves 0,1) + out[0]=0 (wave 2 lane 0)
//   blocks 173..180: fw1/fw2 -> wff chunks (4 chunks/block)
// Legal fusion: wf/wff/wf3 are consumed by k3/k4 which launch AFTER kB.
__global__ void kB(const float* __restrict__ sup, const float* __restrict__ qry,
                   const unsigned short* __restrict__ wf1, const float* __restrict__ gb1,
                   const float* __restrict__ w2, const float* __restrict__ w3,
                   const float* __restrict__ w4,
                   const float* __restrict__ fw1, const float* __restrict__ fw2,
                   const float* __restrict__ fw3,
                   float* __restrict__ ws, unsigned short* __restrict__ wf,
                   unsigned short* __restrict__ wff, unsigned short* __restrict__ wf3,
                   float* __restrict__ out) {
    __shared__ short Xf[4608];        // 9 KB: frag kk at kk*1024 bytes
    int bid = blockIdx.x;
    int t = threadIdx.x;
    int w = t >> 6, l = t & 63;
    int g = l >> 4, c = l & 15;

    if (bid >= 160) {
        if (bid < 172) {              // g-weight frags
            int cid = (bid - 160) * 4 + w;   // 0..47 = L*16+tt
            int L = cid >> 4, tt = cid & 15;
            const float* W = (L == 0) ? w2 : ((L == 1) ? w3 : w4);
            int nn = tt * 16 + (l & 15);
            #pragma unroll
            for (int kk = 0; kk < 8; ++kk) {
                int k0 = kk * 32 + (l >> 4) * 8;
                short8 ov;
                #pragma unroll
                for (int j = 0; j < 8; ++j)
                    ov[j] = (short)f2bf(W[(size_t)(k0 + j) * 256 + nn]);
                *(short8*)((char*)wf + (size_t)cid * 8192 + kk * 1024 + l * 16) = ov;
            }
        } else if (bid == 172) {      // fw3 frags + out init
            if (w < 2) {
                int tt = w;
                int nn = tt * 16 + (l & 15);
                #pragma unroll
                for (int kk = 0; kk < 8; ++kk) {
                    int k0 = kk * 32 + (l >> 4) * 8;
                    short8 ov;
                    #pragma unroll
                    for (int j = 0; j < 8; ++j) {
                        float v = (nn < 29) ? fw3[(size_t)(k0 + j) * 29 + nn] : 0.0f;
                        ov[j] = (short)f2bf(v);
                    }
                    *(short8*)((char*)wf3 + (size_t)tt * 8192 + kk * 1024 + l * 16) = ov;
                }
            } else if (w == 2 && l == 0) {
                out[0] = 0.0f;
            }
        } else {                      // fw1/fw2 frags
            int cid = (bid - 173) * 4 + w;   // 0..31 = Lf*16+tt
            int Lf = cid >> 4, tt = cid & 15;
            const float* W = (Lf == 0) ? fw1 : fw2;
            int nn = tt * 16 + (l & 15);
            #pragma unroll
            for (int kk = 0; kk < 8; ++kk) {
                int k0 = kk * 32 + (l >> 4) * 8;
                short8 ov;
                #pragma unroll
                for (int j = 0; j < 8; ++j)
                    ov[j] = (short)f2bf(W[(size_t)(k0 + j) * 256 + nn]);
                *(short8*)((char*)wff + (size_t)cid * 8192 + kk * 1024 + l * 16) = ov;
            }
        }
        return;
    }

    // ---- layer-1 path: one cell, 16 rows (single m-frag)
    bool isA = (bid < 40);
    int S = isA ? 0 : 1;
    int cell = isA ? bid : (bid - 40);
    const float* src = (isA ? sup : qry) + (size_t)cell * 4096;
    float* dst0 = ws + (isA ? A_OFF_F : B_OFF_F);
    char* Xb = (char*)Xf;

    // stage X frags (kk split across waves): k = kk*32+g*8+j, n = c
    for (int kk = w; kk < 9; kk += 4) {
        int kbase = kk * 32 + g * 8;
        float v[8];
        #pragma unroll
        for (int j = 0; j < 8; ++j) {
            int kb = kbase + j;
            float x;
            if (kb < 256)       x = src[(size_t)kb * 16 + c];
            else if (kb == 256) x = (float)(c >> 2) * 0.25f;
            else if (kb == 257) x = (float)(c & 3) * 0.25f;
            else                x = 0.0f;
            v[j] = x;
        }
        uint4 hv;
        hv.x = cvt_pk_bf16(v[0], v[1]);
        hv.y = cvt_pk_bf16(v[2], v[3]);
        hv.z = cvt_pk_bf16(v[4], v[5]);
        hv.w = cvt_pk_bf16(v[6], v[7]);
        *(uint4*)(Xb + (size_t)kk * 1024 + l * 16) = hv;
    }
    __syncthreads();

    // wave w -> outcols [w*64, +64)
    const char* wbase = (const char*)wf1 + (size_t)(S * 16 + w * 4) * 9216;
    short8 wcur[4];
    #pragma unroll
    for (int tti = 0; tti < 4; ++tti)
        wcur[tti] = *(const short8*)(wbase + (size_t)tti * 9216 + l * 16);

    f32x4 acc[4];
    #pragma unroll
    for (int tti = 0; tti < 4; ++tti) acc[tti] = (f32x4){0.f, 0.f, 0.f, 0.f};

    #pragma unroll
    for (int kk = 0; kk < 9; ++kk) {
        int kn = kk + 1; if (kn > 8) kn = 8;
        short8 wnxt[4];
        #pragma unroll
        for (int tti = 0; tti < 4; ++tti)
            wnxt[tti] = *(const short8*)(wbase + (size_t)tti * 9216 + kn * 1024 + l * 16);
        short8 h = *(const short8*)(Xb + (size_t)kk * 1024 + l * 16);
        #pragma unroll
        for (int tti = 0; tti < 4; ++tti)
            acc[tti] = mfma16(wcur[tti], h, acc[tti]);
        #pragma unroll
        for (int tti = 0; tti < 4; ++tti) wcur[tti] = wnxt[tti];
    }

    // epilogue: row = cell*16 + c, col = w*64 + tti*16 + g*4 + r
    #pragma unroll
    for (int tti = 0; tti < 4; ++tti) {
        int col0 = w * 64 + tti * 16 + g * 4;
        float4 bv = {0.f, 0.f, 0.f, 0.f};
        if (S == 0) bv = *(const float4*)(gb1 + col0);
        int row = cell * 16 + c;
        float4 o;
        o.x = acc[tti][0] + bv.x;
        o.y = acc[tti][1] + bv.y;
        o.z = acc[tti][2] + bv.z;
        o.w = acc[tti][3] + bv.w;
        *(float4*)(dst0 + (size_t)row * 256 + col0) = o;
    }
}

// ---------------- kernel 3: g-MLP layers 2..4 + pair-sum (R12 verified, unchanged) ------
// grid = 1200 blocks = (cell, half): 128 pairs. 512 threads = 8 waves (wp x wn = 2x4).
__launch_bounds__(512, 4)
__global__ void k3_g(const float* __restrict__ wsA, const float* __restrict__ wsB,
                     const unsigned short* __restrict__ wf,
                     const float* __restrict__ gb2, const float* __restrict__ gb3,
                     const float* __restrict__ gb4, float* __restrict__ xf) {
    __shared__ short Hf[32768];   // 64 KB: frag(m,kk) at (m*8+kk)*1024 bytes, m 0..7
    __shared__ float bs[768];
    int bid = blockIdx.x;
    int bqs = bid >> 1, half = bid & 1;
    int b = bqs / 75, rem = bqs % 75, qi = rem / 5, si = rem % 5;
    int t = threadIdx.x;
    int w = t >> 6, l = t & 63;
    int g = l >> 4, c = l & 15;
    int wp = w >> 2, wn = w & 3;
    char* Hb = (char*)Hf;
    const char* wfb = (const char*)wf;

    if (t < 256) { bs[t] = gb2[t]; bs[256 + t] = gb3[t]; bs[512 + t] = gb4[t]; }

    short8 wcur[4];
    #pragma unroll
    for (int tti = 0; tti < 4; ++tti)
        wcur[tti] = *(const short8*)(wfb + (size_t)(wn * 4 + tti) * 8192 + l * 16);

    {
        const float* Arow = wsA + (size_t)(b * NS + si) * 4096 + c * 256;
        const float* Brow = wsB + (size_t)(b * NQ + qi) * 4096 + (half * 8 + w) * 256;
        #pragma unroll
        for (int kk = 0; kk < 8; ++kk) {
            const float* ap = Arow + kk * 32 + g * 8;
            const float* bp = Brow + kk * 32 + g * 8;
            float4 a0 = *(const float4*)ap, a1 = *(const float4*)(ap + 4);
            float4 b0 = *(const float4*)bp, b1 = *(const float4*)(bp + 4);
            uint4 hv;
            hv.x = cvt_pk_bf16(fmaxf(a0.x + b0.x, 0.f), fmaxf(a0.y + b0.y, 0.f));
            hv.y = cvt_pk_bf16(fmaxf(a0.z + b0.z, 0.f), fmaxf(a0.w + b0.w, 0.f));
            hv.z = cvt_pk_bf16(fmaxf(a1.x + b1.x, 0.f), fmaxf(a1.y + b1.y, 0.f));
            hv.w = cvt_pk_bf16(fmaxf(a1.z + b1.z, 0.f), fmaxf(a1.w + b1.w, 0.f));
            *(uint4*)(Hb + (size_t)(w * 8 + kk) * 1024 + l * 16) = hv;
        }
    }
    __syncthreads();

    #pragma unroll 1
    for (int L = 0; L < 3; ++L) {
        f32x4 acc[4][4];
        #pragma unroll
        for (int pg = 0; pg < 4; ++pg)
            #pragma unroll
            for (int tti = 0; tti < 4; ++tti)
                acc[pg][tti] = (f32x4){0.f, 0.f, 0.f, 0.f};

        #pragma unroll
        for (int kk = 0; kk < 8; ++kk) {
            int s = L * 8 + kk + 1; if (s > 23) s = 23;
            int Ln = s >> 3, kn = s & 7;
            short8 wnxt[4];
            #pragma unroll
            for (int tti = 0; tti < 4; ++tti)
                wnxt[tti] = *(const short8*)(wfb +
                    (size_t)(Ln * 16 + wn * 4 + tti) * 8192 + kn * 1024 + l * 16);
            #pragma unroll
            for (int pg = 0; pg < 4; ++pg) {
                short8 h = *(const short8*)(Hb +
                    (size_t)((wp * 4 + pg) * 8 + kk) * 1024 + l * 16);
                #pragma unroll
                for (int tti = 0; tti < 4; ++tti)
                    acc[pg][tti] = mfma16(wcur[tti], h, acc[pg][tti]);
            }
            #pragma unroll
            for (int tti = 0; tti < 4; ++tti) wcur[tti] = wnxt[tti];
        }

        float4 bv[4];
        #pragma unroll
        for (int tti = 0; tti < 4; ++tti)
            bv[tti] = *(const float4*)(bs + L * 256 + wn * 64 + tti * 16 + g * 4);

        if (L < 2) {
            __syncthreads();
            #pragma unroll
            for (int pg = 0; pg < 4; ++pg) {
                int m = wp * 4 + pg;
                #pragma unroll
                for (int tti = 0; tti < 4; ++tti) {
                    uint2 q;
                    q.x = cvt_pk_bf16(fmaxf(acc[pg][tti][0] + bv[tti].x, 0.f),
                                      fmaxf(acc[pg][tti][1] + bv[tti].y, 0.f));
                    q.y = cvt_pk_bf16(fmaxf(acc[pg][tti][2] + bv[tti].z, 0.f),
                                      fmaxf(acc[pg][tti][3] + bv[tti].w, 0.f));
                    int kk2 = wn * 2 + (tti >> 1);
                    int dlane = ((tti & 1) * 2 + (g >> 1)) * 16 + c;
                    *(uint2*)(Hb + (size_t)(m * 8 + kk2) * 1024 + dlane * 16 + (g & 1) * 8) = q;
                }
            }
            __syncthreads();
        } else {
            #pragma unroll
            for (int tti = 0; tti < 4; ++tti) {
                float s0 = 0.f, s1 = 0.f, s2 = 0.f, s3 = 0.f;
                #pragma unroll
                for (int pg = 0; pg < 4; ++pg) {
                    s0 += fmaxf(acc[pg][tti][0] + bv[tti].x, 0.f);
                    s1 += fmaxf(acc[pg][tti][1] + bv[tti].y, 0.f);
                    s2 += fmaxf(acc[pg][tti][2] + bv[tti].z, 0.f);
                    s3 += fmaxf(acc[pg][tti][3] + bv[tti].w, 0.f);
                }
                #pragma unroll
                for (int d = 1; d < 16; d <<= 1) {
                    s0 += __shfl_xor(s0, d); s1 += __shfl_xor(s1, d);
                    s2 += __shfl_xor(s2, d); s3 += __shfl_xor(s3, d);
                }
                if (c == 0) {
                    float4 o = {s0, s1, s2, s3};
                    *(float4*)(xf + (((size_t)bqs * 2 + half) * 2 + wp) * 256 +
                               wn * 64 + tti * 16 + g * 4) = o;
                }
            }
        }
    }
}

// ---------------- kernel 4: f-MLP via MFMA + sigmoid + MSE loss (verified, unchanged) ---
__launch_bounds__(512, 1)
__global__ void k4_f(const float* __restrict__ xf,
                     const unsigned short* __restrict__ wff,
                     const unsigned short* __restrict__ wf3,
                     const float* __restrict__ fb1, const float* __restrict__ fb2,
                     const float* __restrict__ fb3,
                     const float* __restrict__ fw4, const float* __restrict__ fb4,
                     const int* __restrict__ sy, const int* __restrict__ qy,
                     float* __restrict__ out) {
    __shared__ short Hf[16384];   // 32 KB: frag(m,kk) at (m*8+kk)*1024, m 0..3
    __shared__ float bs[512];
    __shared__ float bs3[32];
    __shared__ float y3[64][32];
    int bid = blockIdx.x;
    int t = threadIdx.x;
    int w = t >> 6, l = t & 63;
    int g = l >> 4, c = l & 15;
    char* Hb = (char*)Hf;
    const char* wfb = (const char*)wff;

    bs[t & 511] = (t < 256) ? fb1[t] : fb2[t - 256];
    if (t < 32) bs3[t] = (t < 29) ? fb3[t] : 0.0f;

    for (int fi = w; fi < 32; fi += 8) {
        int m = fi >> 3, kk = fi & 7;
        int row = bid * 64 + m * 16 + c;
        if (row > 599) row = 599;
        const float* xr = xf + (size_t)row * 1024;
        int kb = kk * 32 + g * 8;
        float v[8];
        #pragma unroll
        for (int j = 0; j < 8; ++j) {
            int f = kb + j;
            v[j] = xr[f] + xr[256 + f] + xr[512 + f] + xr[768 + f];
        }
        uint4 hv;
        hv.x = cvt_pk_bf16(v[0], v[1]);
        hv.y = cvt_pk_bf16(v[2], v[3]);
        hv.z = cvt_pk_bf16(v[4], v[5]);
        hv.w = cvt_pk_bf16(v[6], v[7]);
        *(uint4*)(Hb + (size_t)(m * 8 + kk) * 1024 + l * 16) = hv;
    }
    __syncthreads();

    int wp = w >> 2, wn = w & 3;
    short8 wcur[4];
    #pragma unroll
    for (int tti = 0; tti < 4; ++tti)
        wcur[tti] = *(const short8*)(wfb + (size_t)(wn * 4 + tti) * 8192 + l * 16);

    #pragma unroll 1
    for (int L = 0; L < 2; ++L) {
        f32x4 acc[2][4];
        #pragma unroll
        for (int pg = 0; pg < 2; ++pg)
            #pragma unroll
            for (int tti = 0; tti < 4; ++tti)
                acc[pg][tti] = (f32x4){0.f, 0.f, 0.f, 0.f};

        #pragma unroll
        for (int kk = 0; kk < 8; ++kk) {
            int s = L * 8 + kk + 1; if (s > 15) s = 15;
            int Ln = s >> 3, kn = s & 7;
            short8 wnxt[4];
            #pragma unroll
            for (int tti = 0; tti < 4; ++tti)
                wnxt[tti] = *(const short8*)(wfb +
                    (size_t)(Ln * 16 + wn * 4 + tti) * 8192 + kn * 1024 + l * 16);
            #pragma unroll
            for (int pg = 0; pg < 2; ++pg) {
                short8 h = *(const short8*)(Hb +
                    (size_t)((wp * 2 + pg) * 8 + kk) * 1024 + l * 16);
                #pragma unroll
                for (int tti = 0; tti < 4; ++tti)
                    acc[pg][tti] = mfma16(wcur[tti], h, acc[pg][tti]);
            }
            #pragma unroll
            for (int tti = 0; tti < 4; ++tti) wcur[tti] = wnxt[tti];
        }

        float4 bv[4];
        #pragma unroll
        for (int tti = 0; tti < 4; ++tti)
            bv[tti] = *(const float4*)(bs + L * 256 + wn * 64 + tti * 16 + g * 4);

        __syncthreads();
        #pragma unroll
        for (int pg = 0; pg < 2; ++pg) {
            int m = wp * 2 + pg;
            #pragma unroll
            for (int tti = 0; tti < 4; ++tti) {
                uint2 q;
                q.x = cvt_pk_bf16(fmaxf(acc[pg][tti][0] + bv[tti].x, 0.f),
                                  fmaxf(acc[pg][tti][1] + bv[tti].y, 0.f));
                q.y = cvt_pk_bf16(fmaxf(acc[pg][tti][2] + bv[tti].z, 0.f),
                                  fmaxf(acc[pg][tti][3] + bv[tti].w, 0.f));
                int kk2 = wn * 2 + (tti >> 1);
                int dlane = ((tti & 1) * 2 + (g >> 1)) * 16 + c;
                *(uint2*)(Hb + (size_t)(m * 8 + kk2) * 1024 + dlane * 16 + (g & 1) * 8) = q;
            }
        }
        __syncthreads();
    }

    {
        int m = w >> 1, tt = w & 1;
        f32x4 a3 = {0.f, 0.f, 0.f, 0.f};
        #pragma unroll
        for (int kk = 0; kk < 8; ++kk) {
            short8 wv = *(const short8*)((const char*)wf3 +
                (size_t)(tt * 8 + kk) * 1024 + l * 16);
            short8 h = *(const short8*)(Hb + (size_t)(m * 8 + kk) * 1024 + l * 16);
            a3 = mfma16(wv, h, a3);
        }
        #pragma unroll
        for (int r = 0; r < 4; ++r) {
            int oc = tt * 16 + g * 4 + r;
            float v = a3[r] + bs3[oc];
            y3[m * 16 + c][oc] = v > 0.f ? v : 0.f;
        }
    }
    __syncthreads();

    if (t < 64) {
        int bqs = bid * 64 + t;
        if (bqs < 600) {
            float z = fb4[0];
            #pragma unroll
            for (int k = 0; k < 29; ++k) z += y3[t][k] * fw4[k];
            float score = 1.0f / (1.0f + __expf(-z));
            int b = bqs / 75, rem = bqs % 75, qi = rem / 5, si = rem % 5;
            float label = (sy[b * NS + si] == qy[b * NQ + qi]) ? 1.0f : 0.0f;
            float d = label - score;
            atomicAdd(out, d * d * 0.125f);
        }
    }
}

// ---------------- launch ----------------
extern "C" void kernel_launch(void* const* d_in, const int* in_sizes, int n_in,
                              void* d_out, int out_size, void* d_ws, size_t ws_size,
                              hipStream_t stream) {
    const float* sup = (const float*)d_in[0];
    const float* qry = (const float*)d_in[1];
    const int*   sy  = (const int*)d_in[2];
    const int*   qy  = (const int*)d_in[3];
    const float* gw1 = (const float*)d_in[4];
    const float* gb1 = (const float*)d_in[5];
    const float* gw2 = (const float*)d_in[6];
    const float* gb2 = (const float*)d_in[7];
    const float* gw3 = (const float*)d_in[8];
    const float* gb3 = (const float*)d_in[9];
    const float* gw4 = (const float*)d_in[10];
    const float* gb4 = (const float*)d_in[11];
    const float* fw1 = (const float*)d_in[12];
    const float* fb1 = (const float*)d_in[13];
    const float* fw2 = (const float*)d_in[14];
    const float* fb2 = (const float*)d_in[15];
    const float* fw3 = (const float*)d_in[16];
    const float* fb3 = (const float*)d_in[17];
    const float* fw4 = (const float*)d_in[18];
    const float* fb4 = (const float*)d_in[19];

    float* ws = (float*)d_ws;
    float* A  = ws + A_OFF_F;
    float* B  = ws + B_OFF_F;
    float* xf = ws + XF_OFF_F;
    unsigned short* wf  = (unsigned short*)((char*)d_ws + WF_OFF_BYTES);
    unsigned short* wf1 = (unsigned short*)((char*)d_ws + WF1_OFF_BYTES);
    unsigned short* wff = (unsigned short*)((char*)d_ws + WFF_OFF_BYTES);
    unsigned short* wf3 = (unsigned short*)((char*)d_ws + WF3_OFF_BYTES);
    float* out = (float*)d_out;

    kA<<<32, 64, 0, stream>>>(gw1, wf1);
    kB<<<181, 256, 0, stream>>>(sup, qry, wf1, gb1, gw2, gw3, gw4,
                                fw1, fw2, fw3, ws, wf, wff, wf3, out);
    k3_g<<<1200, 512, 0, stream>>>(A, B, wf, gb2, gb3, gb4, xf);
    k4_f<<<10, 512, 0, stream>>>(xf, wff, wf3, fb1, fb2, fb3, fw4, fb4, sy, qy, out);
}